// Round 1
// baseline (179.666 us; speedup 1.0000x reference)
//
#include <hip/hip_runtime.h>

#define NROWS 8192
#define DDIM  512
#define INV_TAU 14.285714285714286f

typedef short short8 __attribute__((ext_vector_type(8)));
typedef float f32x4 __attribute__((ext_vector_type(4)));

__device__ static inline float bf2f(unsigned short u) {
  return __uint_as_float(((unsigned int)u) << 16);
}
__device__ static inline unsigned short f2bf(float f) {
  unsigned int u = __float_as_uint(f);
  u += 0x7fffu + ((u >> 16) & 1u);   // round-to-nearest-even
  return (unsigned short)(u >> 16);
}

__device__ static inline void load_lds16(const void* g, void* l) {
  __builtin_amdgcn_global_load_lds(
      (const __attribute__((address_space(1))) void*)g,
      (__attribute__((address_space(3))) void*)l, 16, 0, 0);
}

// ---------------- normalize: fp32 rows -> bf16 normalized rows ----------------
__global__ __launch_bounds__(256) void norm_kernel(
    const float* __restrict__ zi, const float* __restrict__ zj,
    unsigned short* __restrict__ ziN, unsigned short* __restrict__ zjN) {
  int rid = blockIdx.x * 4 + (threadIdx.x >> 6);   // 0..16383
  int lane = threadIdx.x & 63;
  const float* src;
  unsigned short* dst;
  if (rid < NROWS) { src = zi + (size_t)rid * DDIM; dst = ziN + (size_t)rid * DDIM; }
  else             { src = zj + (size_t)(rid - NROWS) * DDIM; dst = zjN + (size_t)(rid - NROWS) * DDIM; }
  float4 v0 = *(const float4*)(src + lane * 4);
  float4 v1 = *(const float4*)(src + 256 + lane * 4);
  float ss = v0.x*v0.x + v0.y*v0.y + v0.z*v0.z + v0.w*v0.w
           + v1.x*v1.x + v1.y*v1.y + v1.z*v1.z + v1.w*v1.w;
  #pragma unroll
  for (int off = 1; off < 64; off <<= 1) ss += __shfl_xor(ss, off);
  float scale = 1.0f / fmaxf(sqrtf(ss), 1e-8f);
  ushort4 o0, o1;
  o0.x = f2bf(v0.x*scale); o0.y = f2bf(v0.y*scale); o0.z = f2bf(v0.z*scale); o0.w = f2bf(v0.w*scale);
  o1.x = f2bf(v1.x*scale); o1.y = f2bf(v1.y*scale); o1.z = f2bf(v1.z*scale); o1.w = f2bf(v1.w*scale);
  *(ushort4*)(dst + lane * 4) = o0;
  *(ushort4*)(dst + 256 + lane * 4) = o1;
}

// ---------------- zero row/col accumulators (contiguous 16384 floats) --------
__global__ __launch_bounds__(256) void zero_kernel(float* __restrict__ p) {
  p[blockIdx.x * 256 + threadIdx.x] = 0.0f;
}

// ---------------- pos[i] = dot(ziN[i], zjN[i]) / tau --------------------------
__global__ __launch_bounds__(256) void pos_kernel(
    const unsigned short* __restrict__ ziN, const unsigned short* __restrict__ zjN,
    float* __restrict__ pos) {
  int row = blockIdx.x * 4 + (threadIdx.x >> 6);
  int lane = threadIdx.x & 63;
  const unsigned short* a = ziN + (size_t)row * DDIM;
  const unsigned short* b = zjN + (size_t)row * DDIM;
  ushort4 a0 = *(const ushort4*)(a + lane * 4);
  ushort4 a1 = *(const ushort4*)(a + 256 + lane * 4);
  ushort4 b0 = *(const ushort4*)(b + lane * 4);
  ushort4 b1 = *(const ushort4*)(b + 256 + lane * 4);
  float s = bf2f(a0.x)*bf2f(b0.x) + bf2f(a0.y)*bf2f(b0.y)
          + bf2f(a0.z)*bf2f(b0.z) + bf2f(a0.w)*bf2f(b0.w)
          + bf2f(a1.x)*bf2f(b1.x) + bf2f(a1.y)*bf2f(b1.y)
          + bf2f(a1.z)*bf2f(b1.z) + bf2f(a1.w)*bf2f(b1.w);
  #pragma unroll
  for (int off = 1; off < 64; off <<= 1) s += __shfl_xor(s, off);
  if (lane == 0) pos[row] = s * INV_TAU;
}

// ---------------- fused sim GEMM + exp + row/col sum --------------------------
// 128x128 tile, BK=32, 4 waves (2x2), 4x4 16x16x32 frags per wave (m97 shape)
__global__ __launch_bounds__(256) void sim_kernel(
    const unsigned short* __restrict__ ziN, const unsigned short* __restrict__ zjN,
    float* __restrict__ row_sum, float* __restrict__ col_sum) {
  __shared__ unsigned short As[128 * 32];  // [row][k] 64B rows
  __shared__ unsigned short Bs[128 * 32];
  const int tid  = threadIdx.x;
  const int lane = tid & 63;
  const int wid  = tid >> 6;
  const int wr   = wid >> 1, wc = wid & 1;      // 2x2 waves, 64x64 each
  const int brow = blockIdx.y * 128;
  const int bcol = blockIdx.x * 128;

  f32x4 acc[4][4] = {};

  // staging: thread t covers row t/4 (of 64 per issue), col (t&3)*8
  const int srow = tid >> 2;
  const int scol = (tid & 3) * 8;
  const unsigned short* gA = ziN + (size_t)(brow + srow) * DDIM + scol;
  const unsigned short* gB = zjN + (size_t)(bcol + srow) * DDIM + scol;
  char* ldsA = (char*)As + tid * 16;
  char* ldsB = (char*)Bs + tid * 16;

  const int fr = lane & 15;          // frag row/col within 16
  const int kc = (lane >> 4) * 8;    // k-chunk

  for (int k0 = 0; k0 < DDIM; k0 += 32) {
    #pragma unroll
    for (int q = 0; q < 2; ++q) {
      load_lds16(gA + (size_t)q * 64 * DDIM + k0, ldsA + q * 4096);
      load_lds16(gB + (size_t)q * 64 * DDIM + k0, ldsB + q * 4096);
    }
    __syncthreads();
    short8 a[4], b[4];
    #pragma unroll
    for (int m = 0; m < 4; ++m)
      a[m] = *(const short8*)&As[(wr * 64 + m * 16 + fr) * 32 + kc];
    #pragma unroll
    for (int n = 0; n < 4; ++n)
      b[n] = *(const short8*)&Bs[(wc * 64 + n * 16 + fr) * 32 + kc];
    #pragma unroll
    for (int m = 0; m < 4; ++m)
      #pragma unroll
      for (int n = 0; n < 4; ++n)
        acc[m][n] = __builtin_amdgcn_mfma_f32_16x16x32_bf16(a[m], b[n], acc[m][n], 0, 0, 0);
    __syncthreads();
  }

  // epilogue: e = exp((dot-1)/tau) = exp2((dot-1) * inv_tau/ln2), diag -> 0
  const float C = INV_TAU * 1.4426950408889634f;
  const int r0 = brow + wr * 64 + ((lane >> 4) << 2);  // + m*16 + r
  const int c0 = bcol + wc * 64 + fr;                  // + n*16
  #pragma unroll
  for (int m = 0; m < 4; ++m)
    #pragma unroll
    for (int n = 0; n < 4; ++n)
      #pragma unroll
      for (int r = 0; r < 4; ++r) {
        int gi = r0 + m * 16 + r;
        int gj = c0 + n * 16;
        float e = exp2f((acc[m][n][r] - 1.0f) * C);
        acc[m][n][r] = (gi == gj) ? 0.0f : e;
      }

  // column sums: per n, sum over m,r then across the 4 lane-groups
  #pragma unroll
  for (int n = 0; n < 4; ++n) {
    float cs = 0.0f;
    #pragma unroll
    for (int m = 0; m < 4; ++m)
      #pragma unroll
      for (int r = 0; r < 4; ++r) cs += acc[m][n][r];
    cs += __shfl_xor(cs, 16);
    cs += __shfl_xor(cs, 32);
    if (lane < 16) atomicAdd(&col_sum[bcol + wc * 64 + n * 16 + lane], cs);
  }
  // row sums: per (m,r), sum over n then across the 16 lanes of the group
  #pragma unroll
  for (int m = 0; m < 4; ++m)
    #pragma unroll
    for (int r = 0; r < 4; ++r) {
      float rs = acc[m][0][r] + acc[m][1][r] + acc[m][2][r] + acc[m][3][r];
      rs += __shfl_xor(rs, 1);
      rs += __shfl_xor(rs, 2);
      rs += __shfl_xor(rs, 4);
      rs += __shfl_xor(rs, 8);
      if (fr == 0) atomicAdd(&row_sum[r0 + m * 16 + r], rs);
    }
}

// ---------------- finalize: 3 scalars ----------------------------------------
__global__ __launch_bounds__(256) void finalize_kernel(
    const float* __restrict__ row_sum, const float* __restrict__ col_sum,
    const float* __restrict__ pos, float* __restrict__ out) {
  __shared__ float sA[4], sB[4];
  float sa = 0.0f, sb = 0.0f;
  for (int i = threadIdx.x; i < NROWS; i += 256) {
    float p = pos[i];
    sa += (INV_TAU + __logf(row_sum[i])) - p;
    sb += (INV_TAU + __logf(col_sum[i])) - p;
  }
  #pragma unroll
  for (int off = 1; off < 64; off <<= 1) {
    sa += __shfl_xor(sa, off);
    sb += __shfl_xor(sb, off);
  }
  if ((threadIdx.x & 63) == 0) { sA[threadIdx.x >> 6] = sa; sB[threadIdx.x >> 6] = sb; }
  __syncthreads();
  if (threadIdx.x == 0) {
    float ta = sA[0] + sA[1] + sA[2] + sA[3];
    float tb = sB[0] + sB[1] + sB[2] + sB[3];
    float e2t = ta / (float)NROWS;
    float t2e = tb / (float)NROWS;
    out[0] = 0.5f * (e2t + t2e);
    out[1] = e2t;
    out[2] = t2e;
  }
}

extern "C" void kernel_launch(void* const* d_in, const int* in_sizes, int n_in,
                              void* d_out, int out_size, void* d_ws, size_t ws_size,
                              hipStream_t stream) {
  const float* z_i = (const float*)d_in[0];
  const float* z_j = (const float*)d_in[1];
  float* out = (float*)d_out;
  char* ws = (char*)d_ws;
  unsigned short* ziN = (unsigned short*)ws;                       // 8 MB
  unsigned short* zjN = (unsigned short*)(ws + 8388608);           // 8 MB
  float* row_sum = (float*)(ws + 16777216);                        // 32 KB
  float* col_sum = row_sum + NROWS;                                // 32 KB (contiguous)
  float* pos     = col_sum + NROWS;                                // 32 KB

  norm_kernel<<<4096, 256, 0, stream>>>(z_i, z_j, ziN, zjN);
  zero_kernel<<<64, 256, 0, stream>>>(row_sum);                    // zeros row+col (contiguous)
  pos_kernel<<<2048, 256, 0, stream>>>(ziN, zjN, pos);
  dim3 grid(64, 64);
  sim_kernel<<<grid, 256, 0, stream>>>(ziN, zjN, row_sum, col_sum);
  finalize_kernel<<<1, 256, 0, stream>>>(row_sum, col_sum, pos, out);
}

// Round 2
// 165.835 us; speedup vs baseline: 1.0834x; 1.0834x over previous
//
#include <hip/hip_runtime.h>

#define NROWS 8192
#define DDIM  512
#define INV_TAU 14.285714285714286f

typedef short short8 __attribute__((ext_vector_type(8)));
typedef float f32x4 __attribute__((ext_vector_type(4)));

__device__ static inline float bf2f(unsigned short u) {
  return __uint_as_float(((unsigned int)u) << 16);
}
__device__ static inline unsigned short f2bf(float f) {
  unsigned int u = __float_as_uint(f);
  u += 0x7fffu + ((u >> 16) & 1u);   // round-to-nearest-even
  return (unsigned short)(u >> 16);
}

__device__ static inline void load_lds16(const void* g, void* l) {
  __builtin_amdgcn_global_load_lds(
      (const __attribute__((address_space(1))) void*)g,
      (__attribute__((address_space(3))) void*)l, 16, 0, 0);
}

// ---------------- normalize: fp32 rows -> bf16 normalized rows ----------------
__global__ __launch_bounds__(256) void norm_kernel(
    const float* __restrict__ zi, const float* __restrict__ zj,
    unsigned short* __restrict__ ziN, unsigned short* __restrict__ zjN) {
  int rid = blockIdx.x * 4 + (threadIdx.x >> 6);   // 0..16383
  int lane = threadIdx.x & 63;
  const float* src;
  unsigned short* dst;
  if (rid < NROWS) { src = zi + (size_t)rid * DDIM; dst = ziN + (size_t)rid * DDIM; }
  else             { src = zj + (size_t)(rid - NROWS) * DDIM; dst = zjN + (size_t)(rid - NROWS) * DDIM; }
  float4 v0 = *(const float4*)(src + lane * 4);
  float4 v1 = *(const float4*)(src + 256 + lane * 4);
  float ss = v0.x*v0.x + v0.y*v0.y + v0.z*v0.z + v0.w*v0.w
           + v1.x*v1.x + v1.y*v1.y + v1.z*v1.z + v1.w*v1.w;
  #pragma unroll
  for (int off = 1; off < 64; off <<= 1) ss += __shfl_xor(ss, off);
  float scale = 1.0f / fmaxf(sqrtf(ss), 1e-8f);
  ushort4 o0, o1;
  o0.x = f2bf(v0.x*scale); o0.y = f2bf(v0.y*scale); o0.z = f2bf(v0.z*scale); o0.w = f2bf(v0.w*scale);
  o1.x = f2bf(v1.x*scale); o1.y = f2bf(v1.y*scale); o1.z = f2bf(v1.z*scale); o1.w = f2bf(v1.w*scale);
  *(ushort4*)(dst + lane * 4) = o0;
  *(ushort4*)(dst + 256 + lane * 4) = o1;
}

// ---------------- zero row/col accumulators (contiguous 16384 floats) --------
__global__ __launch_bounds__(256) void zero_kernel(float* __restrict__ p) {
  p[blockIdx.x * 256 + threadIdx.x] = 0.0f;
}

// ---------------- pos[i] = dot(ziN[i], zjN[i]) / tau --------------------------
__global__ __launch_bounds__(256) void pos_kernel(
    const unsigned short* __restrict__ ziN, const unsigned short* __restrict__ zjN,
    float* __restrict__ pos) {
  int row = blockIdx.x * 4 + (threadIdx.x >> 6);
  int lane = threadIdx.x & 63;
  const unsigned short* a = ziN + (size_t)row * DDIM;
  const unsigned short* b = zjN + (size_t)row * DDIM;
  ushort4 a0 = *(const ushort4*)(a + lane * 4);
  ushort4 a1 = *(const ushort4*)(a + 256 + lane * 4);
  ushort4 b0 = *(const ushort4*)(b + lane * 4);
  ushort4 b1 = *(const ushort4*)(b + 256 + lane * 4);
  float s = bf2f(a0.x)*bf2f(b0.x) + bf2f(a0.y)*bf2f(b0.y)
          + bf2f(a0.z)*bf2f(b0.z) + bf2f(a0.w)*bf2f(b0.w)
          + bf2f(a1.x)*bf2f(b1.x) + bf2f(a1.y)*bf2f(b1.y)
          + bf2f(a1.z)*bf2f(b1.z) + bf2f(a1.w)*bf2f(b1.w);
  #pragma unroll
  for (int off = 1; off < 64; off <<= 1) s += __shfl_xor(s, off);
  if (lane == 0) pos[row] = s * INV_TAU;
}

// ---------------- fused sim GEMM + exp + row/col sum --------------------------
// 256x256 tile, BK=64, 8 waves (2x4), 4 phases/K-tile, dbuf LDS, counted vmcnt.
// LDS layout per buffer b (shorts): A[256][64] at b*32768, B[256][64] at b*32768+16384.
// Swizzle: LDS[row][chunk] = G[row][chunk ^ (row&7)], chunk = 16B unit (8 bf16).
__global__ __launch_bounds__(512, 2) void sim_kernel(
    const unsigned short* __restrict__ ziN, const unsigned short* __restrict__ zjN,
    float* __restrict__ row_sum, float* __restrict__ col_sum) {
  __shared__ unsigned short lds[65536];   // 128 KiB
  const int tid  = threadIdx.x;
  const int lane = tid & 63;
  const int wid  = tid >> 6;
  const int wr   = wid >> 2;        // 0..1  (m-half: 128 rows)
  const int wc   = wid & 3;         // 0..3  (n-quarter: 64 cols)
  const int fr   = lane & 15;
  const int g    = lane >> 4;
  const int brow = blockIdx.y * 256;
  const int bcol = blockIdx.x * 256;

  f32x4 acc[8][4] = {};
  short8 bfrag[4][2];
  short8 afrag[2][2];

  // stage one half-tile (128 rows x 64 cols) of operand G at k-tile kt.
  // ldsbase in shorts. 2 x global_load_lds_dwordx4 per thread, linear dest,
  // pre-swizzled source (both-sides-or-neither rule).
  auto stage = [&](const unsigned short* __restrict__ G, int grow0, int kt, int ldsbase) {
    #pragma unroll
    for (int rr = 0; rr < 2; ++rr) {
      int idx = rr * 512 + tid;
      int row = idx >> 3;
      int sc  = (idx & 7) ^ (row & 7);
      load_lds16(G + (size_t)(grow0 + row) * DDIM + kt * 64 + sc * 8,
                 (char*)lds + ldsbase * 2 + idx * 16);
    }
  };
  #define ABASE(kt,h) ((((kt)&1)*32768) + (h)*8192)
  #define BBASE(kt,h) ((((kt)&1)*32768) + 16384 + (h)*8192)

  // ---- prologue: stage B(0), A(0), B(1); counted wait (B(1) may stay in flight)
  stage(zjN, bcol + 0,   0, BBASE(0,0));
  stage(zjN, bcol + 128, 0, BBASE(0,1));
  stage(ziN, brow + 0,   0, ABASE(0,0));
  stage(ziN, brow + 128, 0, ABASE(0,1));
  stage(zjN, bcol + 0,   1, BBASE(1,0));
  stage(zjN, bcol + 128, 1, BBASE(1,1));
  asm volatile("s_waitcnt vmcnt(4)" ::: "memory");
  __builtin_amdgcn_s_barrier();

  // ---- main loop: 8 K-tiles x 4 phases
  for (int kt = 0; kt < 8; ++kt) {
    const int bufs = (kt & 1) * 32768;
    #pragma unroll
    for (int q = 0; q < 4; ++q) {
      // ds-reads for this phase (current K-tile)
      if (q == 0) {
        #pragma unroll
        for (int n = 0; n < 4; ++n)
          #pragma unroll
          for (int kk = 0; kk < 2; ++kk) {
            int r  = wc * 64 + n * 16 + fr;
            int ch = (kk * 4 + g) ^ (r & 7);
            bfrag[n][kk] = *(const short8*)&lds[bufs + 16384 + r * 64 + ch * 8];
          }
      }
      #pragma unroll
      for (int i = 0; i < 2; ++i)
        #pragma unroll
        for (int kk = 0; kk < 2; ++kk) {
          int r  = wr * 128 + (q * 2 + i) * 16 + fr;
          int ch = (kk * 4 + g) ^ (r & 7);
          afrag[i][kk] = *(const short8*)&lds[bufs + r * 64 + ch * 8];
        }
      // stage-ahead: A one K-tile ahead, B two K-tiles ahead (slots free by then)
      if (q == 0 && kt + 1 < 8) stage(ziN, brow + 0,   kt + 1, ABASE(kt + 1, 0));
      if (q == 1 && kt + 1 < 8) stage(ziN, brow + 128, kt + 1, ABASE(kt + 1, 1));
      if (q == 2 && kt + 2 < 8) stage(zjN, bcol + 0,   kt + 2, BBASE(kt + 2, 0));
      if (q == 3) {
        if (kt + 2 < 8) stage(zjN, bcol + 128, kt + 2, BBASE(kt + 2, 1));
        // counted wait: newest 4 loads (B(kt+2)) may stay in flight;
        // guarantees A(kt+1), B(kt+1) landed. Tail K-tiles drain fully.
        if (kt < 6) asm volatile("s_waitcnt vmcnt(4)" ::: "memory");
        else        asm volatile("s_waitcnt vmcnt(0)" ::: "memory");
      }
      __builtin_amdgcn_s_barrier();
      asm volatile("s_waitcnt lgkmcnt(0)" ::: "memory");
      __builtin_amdgcn_sched_barrier(0);
      __builtin_amdgcn_s_setprio(1);
      #pragma unroll
      for (int i = 0; i < 2; ++i)
        #pragma unroll
        for (int n = 0; n < 4; ++n) {
          acc[q * 2 + i][n] = __builtin_amdgcn_mfma_f32_16x16x32_bf16(
              afrag[i][0], bfrag[n][0], acc[q * 2 + i][n], 0, 0, 0);
          acc[q * 2 + i][n] = __builtin_amdgcn_mfma_f32_16x16x32_bf16(
              afrag[i][1], bfrag[n][1], acc[q * 2 + i][n], 0, 0, 0);
        }
      __builtin_amdgcn_s_setprio(0);
      __builtin_amdgcn_s_barrier();
    }
  }

  // ---- epilogue: e = exp2((dot-1)*C), diag -> 0, row/col partial sums
  const float Cc = INV_TAU * 1.4426950408889634f;
  const int r0 = brow + wr * 128 + g * 4;   // + m*16 + r
  const int c0 = bcol + wc * 64 + fr;       // + n*16
  #pragma unroll
  for (int m = 0; m < 8; ++m)
    #pragma unroll
    for (int n = 0; n < 4; ++n)
      #pragma unroll
      for (int r = 0; r < 4; ++r) {
        int gi = r0 + m * 16 + r;
        int gj = c0 + n * 16;
        float e = exp2f((acc[m][n][r] - 1.0f) * Cc);
        acc[m][n][r] = (gi == gj) ? 0.0f : e;
      }
  // column sums: reduce over m,r then across the 4 lane-groups
  #pragma unroll
  for (int n = 0; n < 4; ++n) {
    float cs = 0.0f;
    #pragma unroll
    for (int m = 0; m < 8; ++m)
      #pragma unroll
      for (int r = 0; r < 4; ++r) cs += acc[m][n][r];
    cs += __shfl_xor(cs, 16);
    cs += __shfl_xor(cs, 32);
    if (lane < 16) atomicAdd(&col_sum[c0 + n * 16], cs);
  }
  // row sums: reduce over n then across the 16 lanes of each group
  #pragma unroll
  for (int m = 0; m < 8; ++m)
    #pragma unroll
    for (int r = 0; r < 4; ++r) {
      float rs = acc[m][0][r] + acc[m][1][r] + acc[m][2][r] + acc[m][3][r];
      rs += __shfl_xor(rs, 1);
      rs += __shfl_xor(rs, 2);
      rs += __shfl_xor(rs, 4);
      rs += __shfl_xor(rs, 8);
      if (fr == 0) atomicAdd(&row_sum[r0 + m * 16 + r], rs);
    }
}

// ---------------- finalize: 3 scalars ----------------------------------------
__global__ __launch_bounds__(256) void finalize_kernel(
    const float* __restrict__ row_sum, const float* __restrict__ col_sum,
    const float* __restrict__ pos, float* __restrict__ out) {
  __shared__ float sA[4], sB[4];
  float sa = 0.0f, sb = 0.0f;
  for (int i = threadIdx.x; i < NROWS; i += 256) {
    float p = pos[i];
    sa += (INV_TAU + __logf(row_sum[i])) - p;
    sb += (INV_TAU + __logf(col_sum[i])) - p;
  }
  #pragma unroll
  for (int off = 1; off < 64; off <<= 1) {
    sa += __shfl_xor(sa, off);
    sb += __shfl_xor(sb, off);
  }
  if ((threadIdx.x & 63) == 0) { sA[threadIdx.x >> 6] = sa; sB[threadIdx.x >> 6] = sb; }
  __syncthreads();
  if (threadIdx.x == 0) {
    float ta = sA[0] + sA[1] + sA[2] + sA[3];
    float tb = sB[0] + sB[1] + sB[2] + sB[3];
    float e2t = ta / (float)NROWS;
    float t2e = tb / (float)NROWS;
    out[0] = 0.5f * (e2t + t2e);
    out[1] = e2t;
    out[2] = t2e;
  }
}

extern "C" void kernel_launch(void* const* d_in, const int* in_sizes, int n_in,
                              void* d_out, int out_size, void* d_ws, size_t ws_size,
                              hipStream_t stream) {
  const float* z_i = (const float*)d_in[0];
  const float* z_j = (const float*)d_in[1];
  float* out = (float*)d_out;
  char* ws = (char*)d_ws;
  unsigned short* ziN = (unsigned short*)ws;                       // 8 MB
  unsigned short* zjN = (unsigned short*)(ws + 8388608);           // 8 MB
  float* row_sum = (float*)(ws + 16777216);                        // 32 KB
  float* col_sum = row_sum + NROWS;                                // 32 KB (contiguous)
  float* pos     = col_sum + NROWS;                                // 32 KB

  norm_kernel<<<4096, 256, 0, stream>>>(z_i, z_j, ziN, zjN);
  zero_kernel<<<64, 256, 0, stream>>>(row_sum);                    // zeros row+col (contiguous)
  pos_kernel<<<2048, 256, 0, stream>>>(ziN, zjN, pos);
  dim3 grid(32, 32);
  sim_kernel<<<grid, 512, 0, stream>>>(ziN, zjN, row_sum, col_sum);
  finalize_kernel<<<1, 256, 0, stream>>>(row_sum, col_sum, pos, out);
}

// Round 3
// 140.917 us; speedup vs baseline: 1.2750x; 1.1768x over previous
//
#include <hip/hip_runtime.h>

#define NROWS 8192
#define DDIM  512
#define INV_TAU 14.285714285714286f

typedef short short8 __attribute__((ext_vector_type(8)));
typedef float f32x4 __attribute__((ext_vector_type(4)));

__device__ static inline float bf2f(unsigned short u) {
  return __uint_as_float(((unsigned int)u) << 16);
}
__device__ static inline unsigned short f2bf(float f) {
  unsigned int u = __float_as_uint(f);
  u += 0x7fffu + ((u >> 16) & 1u);   // round-to-nearest-even
  return (unsigned short)(u >> 16);
}

__device__ static inline void load_lds16(const void* g, void* l) {
  __builtin_amdgcn_global_load_lds(
      (const __attribute__((address_space(1))) void*)g,
      (__attribute__((address_space(3))) void*)l, 16, 0, 0);
}

// ---------------- normalize: fp32 rows -> bf16 normalized rows ----------------
__global__ __launch_bounds__(256) void norm_kernel(
    const float* __restrict__ zi, const float* __restrict__ zj,
    unsigned short* __restrict__ ziN, unsigned short* __restrict__ zjN) {
  int rid = blockIdx.x * 4 + (threadIdx.x >> 6);   // 0..16383
  int lane = threadIdx.x & 63;
  const float* src;
  unsigned short* dst;
  if (rid < NROWS) { src = zi + (size_t)rid * DDIM; dst = ziN + (size_t)rid * DDIM; }
  else             { src = zj + (size_t)(rid - NROWS) * DDIM; dst = zjN + (size_t)(rid - NROWS) * DDIM; }
  float4 v0 = *(const float4*)(src + lane * 4);
  float4 v1 = *(const float4*)(src + 256 + lane * 4);
  float ss = v0.x*v0.x + v0.y*v0.y + v0.z*v0.z + v0.w*v0.w
           + v1.x*v1.x + v1.y*v1.y + v1.z*v1.z + v1.w*v1.w;
  #pragma unroll
  for (int off = 1; off < 64; off <<= 1) ss += __shfl_xor(ss, off);
  float scale = 1.0f / fmaxf(sqrtf(ss), 1e-8f);
  ushort4 o0, o1;
  o0.x = f2bf(v0.x*scale); o0.y = f2bf(v0.y*scale); o0.z = f2bf(v0.z*scale); o0.w = f2bf(v0.w*scale);
  o1.x = f2bf(v1.x*scale); o1.y = f2bf(v1.y*scale); o1.z = f2bf(v1.z*scale); o1.w = f2bf(v1.w*scale);
  *(ushort4*)(dst + lane * 4) = o0;
  *(ushort4*)(dst + 256 + lane * 4) = o1;
}

// ---------------- zero row/col accumulators (contiguous 16384 floats) --------
__global__ __launch_bounds__(256) void zero_kernel(float* __restrict__ p) {
  p[blockIdx.x * 256 + threadIdx.x] = 0.0f;
}

// ---------------- pos[i] = dot(ziN[i], zjN[i]) / tau --------------------------
__global__ __launch_bounds__(256) void pos_kernel(
    const unsigned short* __restrict__ ziN, const unsigned short* __restrict__ zjN,
    float* __restrict__ pos) {
  int row = blockIdx.x * 4 + (threadIdx.x >> 6);
  int lane = threadIdx.x & 63;
  const unsigned short* a = ziN + (size_t)row * DDIM;
  const unsigned short* b = zjN + (size_t)row * DDIM;
  ushort4 a0 = *(const ushort4*)(a + lane * 4);
  ushort4 a1 = *(const ushort4*)(a + 256 + lane * 4);
  ushort4 b0 = *(const ushort4*)(b + lane * 4);
  ushort4 b1 = *(const ushort4*)(b + 256 + lane * 4);
  float s = bf2f(a0.x)*bf2f(b0.x) + bf2f(a0.y)*bf2f(b0.y)
          + bf2f(a0.z)*bf2f(b0.z) + bf2f(a0.w)*bf2f(b0.w)
          + bf2f(a1.x)*bf2f(b1.x) + bf2f(a1.y)*bf2f(b1.y)
          + bf2f(a1.z)*bf2f(b1.z) + bf2f(a1.w)*bf2f(b1.w);
  #pragma unroll
  for (int off = 1; off < 64; off <<= 1) s += __shfl_xor(s, off);
  if (lane == 0) pos[row] = s * INV_TAU;
}

// ---------------- fused sim GEMM + exp + row/col sum --------------------------
// One round: grid 16x16 = 256 blocks, 1/CU. Each block: 512x512 output as
// 4 serpentine 256^2 sub-tiles, continuous 64-iteration virtual-K pipeline.
// BK=32, 2 phases/K-tile (16 MFMA each), 4-slot LDS rotation (3 K-tiles deep),
// steady vmcnt(8). LDS slot (32KB): A 16KB + B 16KB, slab-transposed:
//   offset = slab(row>>4)*1024 + kchunk(k>>3)*256 + (row&15)*16 bytes
// -> global_load_lds dest linear per wave AND ds_read_b128 conflict-free.
__global__ __launch_bounds__(512, 2) void sim_kernel(
    const unsigned short* __restrict__ ziN, const unsigned short* __restrict__ zjN,
    float* __restrict__ row_sum, float* __restrict__ col_sum) {
  __shared__ unsigned short lds[65536];   // 128 KiB = 4 slots x 32KB
  const int tid  = threadIdx.x;
  const int lane = tid & 63;
  const int wid  = tid >> 6;
  const int wr   = wid >> 2;        // 0..1  (m-half: 128 rows of sub-tile)
  const int wc   = wid & 3;         // 0..3  (n-quarter: 64 cols)
  const int fr   = lane & 15;
  const int g    = lane >> 4;
  const int by   = blockIdx.y, bx = blockIdx.x;

  // staging thread-consts: wave w stages slab w of a 128-row half
  const int rowoff = wid * 16 + fr;       // 0..127
  const int koff   = g * 8;               // 0,8,16,24

  f32x4 acc[8][4] = {};
  short8 afrag[4], bfrag[4];

  auto stage_half = [&](const unsigned short* __restrict__ base, int growbase,
                        int kt3, int dstoff) {
    load_lds16(base + (size_t)(growbase + rowoff) * DDIM + kt3 * 32 + koff,
               (char*)lds + dstoff + tid * 16);
  };

  // thread-const pieces of ds_read addresses
  const int ard = wr * 8192 + g * 256 + fr * 16;          // + slot + m*1024
  const int brd = 16384 + wc * 4096 + g * 256 + fr * 16;  // + slot + n*1024

  auto phase_pair = [&](int vk, bool doStage, int vm) {
    const int slot = (vk & 3) * 32768;
    int brow3 = 0, bcol3 = 0, kt3 = 0, slot3 = 0;
    if (doStage) {
      const int vk3 = vk + 3, s3 = vk3 >> 4;
      kt3   = vk3 & 15;
      brow3 = by * 512 + (s3 >> 1) * 256;
      bcol3 = bx * 512 + ((s3 & 1) ^ (s3 >> 1)) * 256;
      slot3 = (vk3 & 3) * 32768;
    }
    // ---------- phase 0: frags (B all, A m0..3), stage A(vk+3)
    #pragma unroll
    for (int n = 0; n < 4; ++n)
      bfrag[n] = *(const short8*)((const char*)lds + slot + brd + n * 1024);
    #pragma unroll
    for (int m = 0; m < 4; ++m)
      afrag[m] = *(const short8*)((const char*)lds + slot + ard + m * 1024);
    if (doStage) {
      stage_half(ziN, brow3,       kt3, slot3);
      stage_half(ziN, brow3 + 128, kt3, slot3 + 8192);
    }
    __builtin_amdgcn_s_barrier();
    asm volatile("s_waitcnt lgkmcnt(0)" ::: "memory");
    __builtin_amdgcn_sched_barrier(0);
    __builtin_amdgcn_s_setprio(1);
    #pragma unroll
    for (int m = 0; m < 4; ++m)
      #pragma unroll
      for (int n = 0; n < 4; ++n)
        acc[m][n] = __builtin_amdgcn_mfma_f32_16x16x32_bf16(
            afrag[m], bfrag[n], acc[m][n], 0, 0, 0);
    __builtin_amdgcn_s_setprio(0);
    __builtin_amdgcn_s_barrier();
    // ---------- phase 1: frags (A m4..7), stage B(vk+3), counted vmcnt
    #pragma unroll
    for (int m = 0; m < 4; ++m)
      afrag[m] = *(const short8*)((const char*)lds + slot + ard + (m + 4) * 1024);
    if (doStage) {
      stage_half(zjN, bcol3,       kt3, slot3 + 16384);
      stage_half(zjN, bcol3 + 128, kt3, slot3 + 16384 + 8192);
    }
    if (vm == 8)      asm volatile("s_waitcnt vmcnt(8)" ::: "memory");
    else if (vm == 4) asm volatile("s_waitcnt vmcnt(4)" ::: "memory");
    else              asm volatile("s_waitcnt vmcnt(0)" ::: "memory");
    __builtin_amdgcn_s_barrier();
    asm volatile("s_waitcnt lgkmcnt(0)" ::: "memory");
    __builtin_amdgcn_sched_barrier(0);
    __builtin_amdgcn_s_setprio(1);
    #pragma unroll
    for (int m = 0; m < 4; ++m)
      #pragma unroll
      for (int n = 0; n < 4; ++n)
        acc[m + 4][n] = __builtin_amdgcn_mfma_f32_16x16x32_bf16(
            afrag[m], bfrag[n], acc[m + 4][n], 0, 0, 0);
    __builtin_amdgcn_s_setprio(0);
    __builtin_amdgcn_s_barrier();
  };

  const float Cc = INV_TAU * 1.4426950408889634f;
  auto epi = [&](int s) {
    const int brow_s = by * 512 + (s >> 1) * 256;
    const int bcol_s = bx * 512 + ((s & 1) ^ (s >> 1)) * 256;
    const int r0 = brow_s + wr * 128 + g * 4;   // + m*16 + r
    const int c0 = bcol_s + wc * 64 + fr;       // + n*16
    #pragma unroll
    for (int m = 0; m < 8; ++m)
      #pragma unroll
      for (int n = 0; n < 4; ++n)
        #pragma unroll
        for (int r = 0; r < 4; ++r) {
          int gi = r0 + m * 16 + r;
          int gj = c0 + n * 16;
          float e = exp2f((acc[m][n][r] - 1.0f) * Cc);
          acc[m][n][r] = (gi == gj) ? 0.0f : e;
        }
    #pragma unroll
    for (int n = 0; n < 4; ++n) {
      float cs = 0.0f;
      #pragma unroll
      for (int m = 0; m < 8; ++m)
        #pragma unroll
        for (int r = 0; r < 4; ++r) cs += acc[m][n][r];
      cs += __shfl_xor(cs, 16);
      cs += __shfl_xor(cs, 32);
      if (lane < 16) atomicAdd(&col_sum[c0 + n * 16], cs);
    }
    #pragma unroll
    for (int m = 0; m < 8; ++m)
      #pragma unroll
      for (int r = 0; r < 4; ++r) {
        float rs = acc[m][0][r] + acc[m][1][r] + acc[m][2][r] + acc[m][3][r];
        rs += __shfl_xor(rs, 1);
        rs += __shfl_xor(rs, 2);
        rs += __shfl_xor(rs, 4);
        rs += __shfl_xor(rs, 8);
        if (fr == 0) atomicAdd(&row_sum[r0 + m * 16 + r], rs);
      }
    // reset accumulator for the next sub-tile
    #pragma unroll
    for (int m = 0; m < 8; ++m)
      #pragma unroll
      for (int n = 0; n < 4; ++n) acc[m][n] = (f32x4){0.f, 0.f, 0.f, 0.f};
  };

  // ---- prologue: stage K-tiles 0,1,2 (all sub-tile 0), keep (1),(2) in flight
  #pragma unroll
  for (int v = 0; v < 3; ++v) {
    const int sl = v * 32768;
    stage_half(ziN, by * 512,       v, sl);
    stage_half(ziN, by * 512 + 128, v, sl + 8192);
    stage_half(zjN, bx * 512,       v, sl + 16384);
    stage_half(zjN, bx * 512 + 128, v, sl + 16384 + 8192);
  }
  asm volatile("s_waitcnt vmcnt(8)" ::: "memory");
  __builtin_amdgcn_s_barrier();

  // ---- main virtual-K loop: 64 K-tiles across 4 sub-tiles
  #pragma unroll 4
  for (int vk = 0; vk < 60; ++vk) {
    phase_pair(vk, true, 8);
    if ((vk & 15) == 15) epi(vk >> 4);
  }
  phase_pair(60, true, 8);
  phase_pair(61, false, 4);
  phase_pair(62, false, 0);
  phase_pair(63, false, 0);
  epi(3);
}

// ---------------- finalize: 3 scalars ----------------------------------------
__global__ __launch_bounds__(256) void finalize_kernel(
    const float* __restrict__ row_sum, const float* __restrict__ col_sum,
    const float* __restrict__ pos, float* __restrict__ out) {
  __shared__ float sA[4], sB[4];
  float sa = 0.0f, sb = 0.0f;
  for (int i = threadIdx.x; i < NROWS; i += 256) {
    float p = pos[i];
    sa += (INV_TAU + __logf(row_sum[i])) - p;
    sb += (INV_TAU + __logf(col_sum[i])) - p;
  }
  #pragma unroll
  for (int off = 1; off < 64; off <<= 1) {
    sa += __shfl_xor(sa, off);
    sb += __shfl_xor(sb, off);
  }
  if ((threadIdx.x & 63) == 0) { sA[threadIdx.x >> 6] = sa; sB[threadIdx.x >> 6] = sb; }
  __syncthreads();
  if (threadIdx.x == 0) {
    float ta = sA[0] + sA[1] + sA[2] + sA[3];
    float tb = sB[0] + sB[1] + sB[2] + sB[3];
    float e2t = ta / (float)NROWS;
    float t2e = tb / (float)NROWS;
    out[0] = 0.5f * (e2t + t2e);
    out[1] = e2t;
    out[2] = t2e;
  }
}

extern "C" void kernel_launch(void* const* d_in, const int* in_sizes, int n_in,
                              void* d_out, int out_size, void* d_ws, size_t ws_size,
                              hipStream_t stream) {
  const float* z_i = (const float*)d_in[0];
  const float* z_j = (const float*)d_in[1];
  float* out = (float*)d_out;
  char* ws = (char*)d_ws;
  unsigned short* ziN = (unsigned short*)ws;                       // 8 MB
  unsigned short* zjN = (unsigned short*)(ws + 8388608);           // 8 MB
  float* row_sum = (float*)(ws + 16777216);                        // 32 KB
  float* col_sum = row_sum + NROWS;                                // 32 KB (contiguous)
  float* pos     = col_sum + NROWS;                                // 32 KB

  norm_kernel<<<4096, 256, 0, stream>>>(z_i, z_j, ziN, zjN);
  zero_kernel<<<64, 256, 0, stream>>>(row_sum);                    // zeros row+col (contiguous)
  pos_kernel<<<2048, 256, 0, stream>>>(ziN, zjN, pos);
  dim3 grid(16, 16);
  sim_kernel<<<grid, 512, 0, stream>>>(ziN, zjN, row_sum, col_sum);
  finalize_kernel<<<1, 256, 0, stream>>>(row_sum, col_sum, pos, out);
}